// Round 8
// baseline (486.144 us; speedup 1.0000x reference)
//
#include <hip/hip_runtime.h>
#include <math.h>

// ---------------------------------------------------------------------------
// SO3 convolution. bf16 MFMA GEMM (complex-as-real); Hermitian-half FFT/IFFT.
// Pipeline: k_fwd_prep (fft fwd [Hermitian bf16 out] + prep_B fused)
//           -> k_beta_A -> k_gemm (MFMA) -> k_inv2 (4-beta gather + radix-2)
// Workspace: yhb 44.7MB | Ab 4.2MB | zh_T 11.2MB (Xfb 8.4MB aliases zh_T:
//   Xfb lifetime fwd_prep->beta_A, zh_T lifetime gemm->inv2 -- disjoint).
// ---------------------------------------------------------------------------

typedef unsigned short u16;
typedef unsigned int   u32;
typedef __attribute__((ext_vector_type(8))) short  short8;   // 8 bf16
typedef __attribute__((ext_vector_type(4))) float  floatx4;

constexpr int LTOT = 5456;

constexpr int LB[17] = {0,1,10,35,84,165,286,455,680,969,
                        1330,1771,2300,2925,3654,4495,5456};

__device__ inline u16 f2bf(float f) {
    u32 u = __float_as_uint(f);
    u += 0x7fff + ((u >> 16) & 1);
    return (u16)(u >> 16);
}
__device__ inline u32 pack2bf(float re, float im) {
    return (u32)f2bf(re) | ((u32)f2bf(im) << 16);
}

// ---------------------------------------------------------------------------
// Fused: blocks [0,4096) = forward FFT2 (radix-2, Hermitian rows 0..15 only,
// bf16-packed out); blocks [4096,4778) = prep_B (yh = D*kernel, bf16).
// Independent work -> overlaps fft's compute with prep's write-bound tail.
// ---------------------------------------------------------------------------
__global__ __launch_bounds__(512) void k_fwd_prep(const float* __restrict__ x,
                                                  const float* __restrict__ Dre,
                                                  const float* __restrict__ Dim,
                                                  const float* __restrict__ ker,
                                                  u32* __restrict__ Xfb,
                                                  u32* __restrict__ yhb) {
    __shared__ float xs[1056];               // [a][g] stride 33
    __shared__ float Gre[1056], Gim[1056];   // [a][k] stride 33
    __shared__ float Wc[32], Ws[32];
    __shared__ float Ds[8][24];
    int tid = threadIdx.x;
    if (blockIdx.x < 4096) {
        // ---------------- forward FFT ----------------
        if (tid < 32) {
            float sv, cv;
            sincosf(6.28318530717958647692f * (float)tid / 32.0f, &sv, &cv);
            Wc[tid] = cv; Ws[tid] = sv;
        }
        const float* src = x + (size_t)blockIdx.x * 1024;
        for (int e = tid; e < 1024; e += 512) xs[(e >> 5) * 33 + (e & 31)] = src[e];
        __syncthreads();
        // pass 1 over g (real input), radix-2: task = (a, k in 0..15)
        {
            int a = tid >> 4, k = tid & 15;
            const float* row = &xs[a * 33];
            float Er = 0.f, Ei = 0.f, Or = 0.f, Oi = 0.f;
#pragma unroll
            for (int h = 0; h < 16; h++) {
                int idx = (2 * h * k) & 31;
                float c = Wc[idx], s = Ws[idx];
                float xe = row[2 * h], xo = row[2 * h + 1];
                Er += xe * c;  Ei -= xe * s;
                Or += xo * c;  Oi -= xo * s;
            }
            float WOr = Or * Wc[k] + Oi * Ws[k];
            float WOi = Oi * Wc[k] - Or * Ws[k];
            Gre[a * 33 + k]      = Er + WOr;
            Gim[a * 33 + k]      = Ei + WOi;
            Gre[a * 33 + k + 16] = Er - WOr;
            Gim[a * 33 + k + 16] = Ei - WOi;
        }
        __syncthreads();
        // pass 2 over a, radix-2; store ONLY rows ma 0..15 (Hermitian half)
        {
            u32* dst = Xfb + (size_t)blockIdx.x * 512;
            int ng = tid & 31, ma = tid >> 5;
            float Er = 0.f, Ei = 0.f, Or = 0.f, Oi = 0.f;
#pragma unroll
            for (int h = 0; h < 16; h++) {
                int idx = (2 * h * ma) & 31;
                float c = Wc[idx], s = Ws[idx];
                float er = Gre[(2 * h) * 33 + ng],      ei = Gim[(2 * h) * 33 + ng];
                float orr = Gre[(2 * h + 1) * 33 + ng], oi = Gim[(2 * h + 1) * 33 + ng];
                Er += er * c + ei * s;   Ei += ei * c - er * s;
                Or += orr * c + oi * s;  Oi += oi * c - orr * s;
            }
            float WOr = Or * Wc[ma] + Oi * Ws[ma];
            float WOi = Oi * Wc[ma] - Or * Ws[ma];
            dst[ma * 32 + ng] = pack2bf(Er + WOr, Ei + WOi);
        }
    } else {
        // ---------------- prep_B: yhb[t2][io] = bf16(D[t2] . ker[io]) ------
        int bid = blockIdx.x - 4096;
        int t0  = bid * 8;
        if (tid < 192) {
            int rr = tid / 24, jj = tid - rr * 24;
            Ds[rr][jj] = (jj < 12) ? Dre[(t0 + rr) * 12 + jj]
                                   : Dim[(t0 + rr) * 12 + jj - 12];
        }
        __syncthreads();
        for (int rep = 0; rep < 4; rep++) {
            int io = rep * 512 + tid;
            const float4* kp = (const float4*)(ker + io * 12);
            float4 ka = kp[0], kb = kp[1], kc = kp[2];
            float kv[12] = {ka.x, ka.y, ka.z, ka.w, kb.x, kb.y, kb.z, kb.w,
                            kc.x, kc.y, kc.z, kc.w};
#pragma unroll
            for (int rr = 0; rr < 8; rr++) {
                float sr = 0.f, si = 0.f;
#pragma unroll
                for (int j = 0; j < 12; j++) {
                    sr += Ds[rr][j]      * kv[j];
                    si += Ds[rr][12 + j] * kv[j];
                }
                yhb[(size_t)(t0 + rr) * 2048 + io] = pack2bf(sr, si);
            }
        }
    }
}

// ---------------------------------------------------------------------------
// Fused beta-contraction + bf16 A-fragment pack. Xfb is Hermitian-half:
// rows ma 0..15 stored; ma>=17 read as conj(Xf[32-ma][(32-ng)&31]).
// Grid: (ma 32) x (zig 64) = 2048 blocks; thread = (zil 2, lq 4, ng 32).
// ---------------------------------------------------------------------------
__global__ __launch_bounds__(256) void k_beta_A(const u32* __restrict__ Xfb,
                                                const float* __restrict__ wf,
                                                u16* __restrict__ Ab) {
    int ma  = blockIdx.x >> 6;
    int zig = blockIdx.x & 63;
    int tid = threadIdx.x;
    int ng  = tid & 31;
    int lq  = (tid >> 5) & 3;
    int zil = tid >> 7;
    int zi  = zig * 2 + zil;
    int z = zi >> 5, i = zi & 31;
    int mh = (ma <= 15) ? ma : ma - 32;
    int nh = (ng <= 15) ? ng : ng - 32;
    int am = mh < 0 ? -mh : mh;
    int an = nh < 0 ? -nh : nh;
    int l0 = am > an ? am : an;
    int lb = lq * 4;

    int isconj = (ma > 16);
    int mau = isconj ? (32 - ma) : ma;
    int ngu = isconj ? ((32 - ng) & 31) : ng;
    if (mau > 15) { mau = 0; ngu = 0; }   // ma==16: l0==16, values unused

    int tl[4];
#pragma unroll
    for (int j = 0; j < 4; j++) {
        int l = lb + j;
        tl[j] = LB[l] + (mh + l) * (2 * l + 1) + (nh + l);
    }
    float2 acc[4];
#pragma unroll
    for (int j = 0; j < 4; j++) acc[j] = make_float2(0.f, 0.f);

    const u32* xp = Xfb + (size_t)zi * 32 * 512 + mau * 32 + ngu;
    float sgn = isconj ? -1.f : 1.f;
#pragma unroll 4
    for (int b = 0; b < 32; b++) {
        u32 pv = xp[(size_t)b * 512];
        float vx = __uint_as_float(pv << 16);
        float vy = sgn * __uint_as_float(pv & 0xffff0000u);
        const float* wfb = wf + b * LTOT;
#pragma unroll
        for (int j = 0; j < 4; j++) {
            if (lb + j >= l0) {
                float w = wfb[tl[j]];
                acc[j].x += w * vx;
                acc[j].y += w * vy;
            }
        }
    }
    int s_i  = i >> 4;
    int kl   = 2 * (i & 15);
    int joff = kl & 7;
    int Lhi  = (kl >> 3) << 4;
#pragma unroll
    for (int j = 0; j < 4; j++) {
        int l = lb + j;
        if (l >= l0) {
            int mi = mh + l, ni = nh + l;
            int s   = 2 * ni + s_i;
            int row = 4 * mi + z;
            u32 pack = pack2bf(acc[j].x, acc[j].y);
            size_t off = (size_t)8192 * l * l + (size_t)s * 4096
                       + ((row >> 4) << 9) + ((Lhi + (row & 15)) << 3) + joff;
            *(u32*)(Ab + off) = pack;
        }
    }
}

// ---------------------------------------------------------------------------
// MFMA GEMM. 512 blocks = sum_l 2*(2l+1), big l first: block = (l, n, oh).
// Output transposed: zh_T[zo][t] (float pairs).
// ---------------------------------------------------------------------------
__global__ __launch_bounds__(256) void k_gemm(const u16* __restrict__ Ab,
                                              const u32* __restrict__ yhb,
                                              float* __restrict__ zhT) {
    __shared__ __align__(16) u16 As[4096];
    __shared__ __align__(16) u16 Bs[2048];

    int rem = blockIdx.x, l, nl = 1;
    for (l = 15; l >= 0; l--) {
        nl = 2 * l + 1;
        int c = nl * 2;
        if (rem < c) break;
        rem -= c;
    }
    int n  = rem >> 1;
    int oh = rem & 1;
    int base = LB[l];
    const u16* Ag = Ab + (size_t)8192 * l * l;
    int S = 2 * nl;

    int tid = threadIdx.x, lane = tid & 63, w = tid >> 6;

    int kh = (tid >> 4) & 3;
    int nu = ((tid >> 6) << 4) + (tid & 15);
    int oo = (oh << 5) + (nu >> 1);
    int cc = nu & 1;

    floatx4 acc[2][4];
#pragma unroll
    for (int a = 0; a < 2; a++)
#pragma unroll
        for (int b = 0; b < 4; b++) acc[a][b] = (floatx4)0.f;

    for (int s = 0; s < S; s++) {
        const uint4* ap = (const uint4*)(Ag + (size_t)s * 4096);
        uint4 a0 = ap[tid * 2], a1 = ap[tid * 2 + 1];
        int k = s >> 1, ih = s & 1;
        const u32* yr = yhb + (size_t)(base + k * nl + n) * 2048
                        + (((ih << 4) + (kh << 2)) << 6) + oo;
        u32 b0 = yr[0], b1 = yr[64], b2 = yr[128], b3 = yr[192];
        u32 p0, p1, p2, p3;
        if (cc == 0) {
            p0 = (b0 & 0xffffu) | ((b0 >> 16) << 16 ^ 0x80000000u);
            p1 = (b1 & 0xffffu) | ((b1 >> 16) << 16 ^ 0x80000000u);
            p2 = (b2 & 0xffffu) | ((b2 >> 16) << 16 ^ 0x80000000u);
            p3 = (b3 & 0xffffu) | ((b3 >> 16) << 16 ^ 0x80000000u);
        } else {
            p0 = (b0 >> 16) | (b0 << 16);
            p1 = (b1 >> 16) | (b1 << 16);
            p2 = (b2 >> 16) | (b2 << 16);
            p3 = (b3 >> 16) | (b3 << 16);
        }
        {
            uint4* aq = (uint4*)&As[tid << 4];
            aq[0] = a0; aq[1] = a1;
            *(uint4*)&Bs[tid << 3] = make_uint4(p0, p1, p2, p3);
        }
        __syncthreads();
        short8 af0 = *(const short8*)&As[((w << 1) + 0) * 512 + (lane << 3)];
        short8 af1 = *(const short8*)&As[((w << 1) + 1) * 512 + (lane << 3)];
#pragma unroll
        for (int nt = 0; nt < 4; nt++) {
            short8 bf = *(const short8*)&Bs[nt * 512 + (lane << 3)];
            acc[0][nt] = __builtin_amdgcn_mfma_f32_16x16x32_bf16(af0, bf, acc[0][nt], 0, 0, 0);
            acc[1][nt] = __builtin_amdgcn_mfma_f32_16x16x32_bf16(af1, bf, acc[1][nt], 0, 0, 0);
        }
        __syncthreads();
    }

    int q = lane >> 4, cn = lane & 15;
#pragma unroll
    for (int mt = 0; mt < 2; mt++) {
#pragma unroll
        for (int nt = 0; nt < 4; nt++) {
            int nu2 = (nt << 4) + cn;
            int o2  = (oh << 5) + (nu2 >> 1);
            int c2  = nu2 & 1;
#pragma unroll
            for (int r = 0; r < 4; r++) {
                int R = (w << 5) + (mt << 4) + (q << 2) + r;
                int m = R >> 2, z = R & 3;
                if (m < nl) {
                    int t  = base + m * nl + n;
                    int zo = (z << 6) + o2;
                    zhT[((size_t)zo * LTOT + t) * 2 + c2] = acc[mt][nt][r];
                }
            }
        }
    }
}

// ---------------------------------------------------------------------------
// Inverse, 4 betas per block: shared zv loads across betas (1 zv + 4 w loads
// per 16 FMA), direct pass-2 global write (no LDS staging).
// Grid: 2048 = (zo 256) x (bq 8); 256 threads; LDS ~17 KB.
// ---------------------------------------------------------------------------
__global__ __launch_bounds__(256) void k_inv2(const float2* __restrict__ zhT,
                                              const float* __restrict__ wi,
                                              const float* __restrict__ bias,
                                              float* __restrict__ out) {
    __shared__ float2 Pb[4 * 528];   // plane p at p*528, rows ma 0..15 stride 33
    __shared__ float Wc[32], Ws[32];
    int tid = threadIdx.x;
    int zo = blockIdx.x >> 3;
    int bq = blockIdx.x & 7;
    int b0 = bq * 4;
    if (tid < 32) {
        float sv, cv;
        sincosf(6.28318530717958647692f * (float)tid / 32.0f, &sv, &cv);
        Wc[tid] = cv; Ws[tid] = sv;
    }
    // ---- gather: thread = (ng 32, rq 8); 2 ma-rows; 4 betas share each zv
    {
        int ng = tid & 31, rq = tid >> 5;
        int nh = (ng <= 15) ? ng : ng - 32;
        int an = nh < 0 ? -nh : nh;
        const float2* zr = zhT + (size_t)zo * LTOT;
        const float* w0p = wi + (size_t)b0 * LTOT;
        const float* w1p = w0p + LTOT;
        const float* w2p = w1p + LTOT;
        const float* w3p = w2p + LTOT;
#pragma unroll
        for (int mr = 0; mr < 2; mr++) {
            int ma = rq + 8 * mr;
            int l0 = ma > an ? ma : an;
            float2 a0 = make_float2(0.f, 0.f), a1 = a0, a2 = a0, a3 = a0;
#pragma unroll
            for (int l = 0; l < 16; l++) {
                if (l >= l0) {
                    int t = LB[l] + (ma + l) * (2 * l + 1) + (nh + l);
                    float2 zv = zr[t];
                    float f0 = w0p[t], f1 = w1p[t], f2 = w2p[t], f3 = w3p[t];
                    a0.x += f0 * zv.x; a0.y += f0 * zv.y;
                    a1.x += f1 * zv.x; a1.y += f1 * zv.y;
                    a2.x += f2 * zv.x; a2.y += f2 * zv.y;
                    a3.x += f3 * zv.x; a3.y += f3 * zv.y;
                }
            }
            int po = ma * 33 + ng;
            Pb[po]            = a0;
            Pb[528 + po]      = a1;
            Pb[2 * 528 + po]  = a2;
            Pb[3 * 528 + po]  = a3;
        }
    }
    __syncthreads();
    // ---- pass 1 (ng -> g), radix-2, in-place: 64 rows x 8 thr = 512 tasks
#pragma unroll
    for (int it = 0; it < 2; it++) {
        int task = tid + it * 256;
        int rowid = task >> 3, q = task & 7;
        float2* prow = &Pb[(rowid >> 4) * 528 + (rowid & 15) * 33];
        float2 row[32];
#pragma unroll
        for (int ngi = 0; ngi < 32; ngi++) row[ngi] = prow[ngi];
        float2 outv[4];
#pragma unroll
        for (int kk = 0; kk < 2; kk++) {
            int k = q + kk * 8;
            float2 E = make_float2(0.f, 0.f), O = make_float2(0.f, 0.f);
#pragma unroll
            for (int h = 0; h < 16; h++) {
                int idx = (2 * h * k) & 31;
                float c = Wc[idx], s = Ws[idx];
                float2 e = row[2 * h], o = row[2 * h + 1];
                E.x += e.x * c - e.y * s;  E.y += e.x * s + e.y * c;
                O.x += o.x * c - o.y * s;  O.y += o.x * s + o.y * c;
            }
            float c = Wc[k], s = Ws[k];
            float2 wO = make_float2(O.x * c - O.y * s, O.x * s + O.y * c);
            outv[kk * 2]     = make_float2(E.x + wO.x, E.y + wO.y);
            outv[kk * 2 + 1] = make_float2(E.x - wO.x, E.y - wO.y);
        }
        prow[q]      = outv[0];
        prow[q + 16] = outv[1];
        prow[q + 8]  = outv[2];
        prow[q + 24] = outv[3];
    }
    __syncthreads();
    // ---- pass 2 (ma -> a): direct store with bias (no staging)
    float bv = bias[zo & 63];
#pragma unroll
    for (int it = 0; it < 2; it++) {
        int task = tid + it * 256;
        int p = task >> 7, rr = task & 127;
        int qa = rr >> 5, g = rr & 31;
        float2 col[16];
        const float2* pc = &Pb[p * 528];
#pragma unroll
        for (int ma = 0; ma < 16; ma++) col[ma] = pc[ma * 33 + g];
        float* dst = out + (size_t)zo * 32768 + (size_t)(b0 + p) * 1024;
#pragma unroll
        for (int jj = 0; jj < 4; jj++) {
            int a = qa * 4 + jj;
            float Ea = col[0].x;
            float Oa = 0.f;
#pragma unroll
            for (int j = 1; j < 8; j++) {
                int idx = ((2 * j) * a) & 31;
                Ea += 2.f * (col[2 * j].x * Wc[idx] - col[2 * j].y * Ws[idx]);
            }
#pragma unroll
            for (int j = 0; j < 8; j++) {
                int idx = ((2 * j + 1) * a) & 31;
                Oa += 2.f * (col[2 * j + 1].x * Wc[idx] - col[2 * j + 1].y * Ws[idx]);
            }
            dst[a * 32 + g]        = (Ea + Oa) * (1.f / 1024.f) + bv;
            dst[(a + 16) * 32 + g] = (Ea - Oa) * (1.f / 1024.f) + bv;
        }
    }
}

// ---------------------------------------------------------------------------
extern "C" void kernel_launch(void* const* d_in, const int* in_sizes, int n_in,
                              void* d_out, int out_size, void* d_ws, size_t ws_size,
                              hipStream_t stream) {
    const float* x    = (const float*)d_in[0];
    const float* ker  = (const float*)d_in[1];
    const float* bias = (const float*)d_in[2];
    const float* wf   = (const float*)d_in[3];
    const float* wi   = (const float*)d_in[4];
    const float* Dre  = (const float*)d_in[5];
    const float* Dim  = (const float*)d_in[6];
    float* out = (float*)d_out;

    // layout: yhb 44.7MB | Ab 4.2MB | zh_T 11.2MB; Xfb (8.4MB) aliases zh_T.
    char* ws = (char*)d_ws;
    u32*    yhb = (u32*)ws;
    u16*    Ab  = (u16*)(ws + 44695552);
    float*  zhT = (float*)(ws + 44695552 + 4194304);
    u32*    Xfb = (u32*)zhT;   // disjoint lifetime vs zh_T

    hipLaunchKernelGGL(k_fwd_prep, dim3(4778), dim3(512), 0, stream,
                       x, Dre, Dim, ker, Xfb, yhb);
    hipLaunchKernelGGL(k_beta_A,   dim3(2048), dim3(256), 0, stream, Xfb, wf, Ab);
    hipLaunchKernelGGL(k_gemm,     dim3(512),  dim3(256), 0, stream, Ab, yhb, zhT);
    hipLaunchKernelGGL(k_inv2,     dim3(2048), dim3(256), 0, stream,
                       (const float2*)zhT, wi, bias, out);
}

// Round 9
// 285.471 us; speedup vs baseline: 1.7030x; 1.7030x over previous
//
#include <hip/hip_runtime.h>
#include <math.h>

// ---------------------------------------------------------------------------
// SO3 convolution. bf16 MFMA GEMM (complex-as-real); Hermitian-half FFT/IFFT.
// Pipeline: k_fft_fwd (Hermitian bf16 out) -> k_prep_B -> k_beta_A
//           -> k_gemm (MFMA) -> k_inv2 (4-beta gather + radix-2)
// R8 lesson: fusing fft+prep into one 512-thr kernel spilled (VGPR cap 128,
// 525 MB scratch traffic) -- keep them separate.
// Workspace: yhb 44.7MB | Ab 4.2MB | zh_T 11.2MB (Xfb 8.4MB aliases zh_T:
//   Xfb lifetime fft->beta_A, zh_T lifetime gemm->inv2 -- disjoint).
// ---------------------------------------------------------------------------

typedef unsigned short u16;
typedef unsigned int   u32;
typedef __attribute__((ext_vector_type(8))) short  short8;   // 8 bf16
typedef __attribute__((ext_vector_type(4))) float  floatx4;

constexpr int LTOT = 5456;

constexpr int LB[17] = {0,1,10,35,84,165,286,455,680,969,
                        1330,1771,2300,2925,3654,4495,5456};

__device__ inline u16 f2bf(float f) {
    u32 u = __float_as_uint(f);
    u += 0x7fff + ((u >> 16) & 1);
    return (u16)(u >> 16);
}
__device__ inline u32 pack2bf(float re, float im) {
    return (u32)f2bf(re) | ((u32)f2bf(im) << 16);
}

// ---------------------------------------------------------------------------
// Forward FFT2 (e^{-i}), radix-2 both passes, 512 threads, one task each.
// Stores ONLY Hermitian-half rows ma 0..15, bf16-packed.
// x: [z][i][b][a][g].   Xfb: [zi*32+b][ma(0..15)][ng] packed bf16 pairs.
// ---------------------------------------------------------------------------
__global__ __launch_bounds__(512) void k_fft_fwd(const float* __restrict__ x,
                                                 u32* __restrict__ Xfb) {
    __shared__ float xs[1056];               // [a][g] stride 33
    __shared__ float Gre[1056], Gim[1056];   // [a][k] stride 33
    __shared__ float Wc[32], Ws[32];
    int tid = threadIdx.x;
    if (tid < 32) {
        float sv, cv;
        sincosf(6.28318530717958647692f * (float)tid / 32.0f, &sv, &cv);
        Wc[tid] = cv; Ws[tid] = sv;
    }
    const float* src = x + (size_t)blockIdx.x * 1024;
    for (int e = tid; e < 1024; e += 512) xs[(e >> 5) * 33 + (e & 31)] = src[e];
    __syncthreads();
    // pass 1 over g (real input), radix-2: task = (a, k in 0..15)
    {
        int a = tid >> 4, k = tid & 15;
        const float* row = &xs[a * 33];
        float Er = 0.f, Ei = 0.f, Or = 0.f, Oi = 0.f;
#pragma unroll
        for (int h = 0; h < 16; h++) {
            int idx = (2 * h * k) & 31;
            float c = Wc[idx], s = Ws[idx];
            float xe = row[2 * h], xo = row[2 * h + 1];
            Er += xe * c;  Ei -= xe * s;
            Or += xo * c;  Oi -= xo * s;
        }
        float WOr = Or * Wc[k] + Oi * Ws[k];
        float WOi = Oi * Wc[k] - Or * Ws[k];
        Gre[a * 33 + k]      = Er + WOr;
        Gim[a * 33 + k]      = Ei + WOi;
        Gre[a * 33 + k + 16] = Er - WOr;
        Gim[a * 33 + k + 16] = Ei - WOi;
    }
    __syncthreads();
    // pass 2 over a, radix-2 combine; store only row ma (0..15)
    {
        u32* dst = Xfb + (size_t)blockIdx.x * 512;
        int ng = tid & 31, ma = tid >> 5;
        float Er = 0.f, Ei = 0.f, Or = 0.f, Oi = 0.f;
#pragma unroll
        for (int h = 0; h < 16; h++) {
            int idx = (2 * h * ma) & 31;
            float c = Wc[idx], s = Ws[idx];
            float er = Gre[(2 * h) * 33 + ng],      ei = Gim[(2 * h) * 33 + ng];
            float orr = Gre[(2 * h + 1) * 33 + ng], oi = Gim[(2 * h + 1) * 33 + ng];
            Er += er * c + ei * s;   Ei += ei * c - er * s;
            Or += orr * c + oi * s;  Oi += oi * c - orr * s;
        }
        float WOr = Or * Wc[ma] + Oi * Ws[ma];
        float WOi = Oi * Wc[ma] - Or * Ws[ma];
        dst[ma * 32 + ng] = pack2bf(Er + WOr, Ei + WOi);
    }
}

// ---------------------------------------------------------------------------
// Build compact bf16 yh: yhb[t2][io] = pack(bf16(re), bf16(im)) of D*kernel.
// (Separate kernel -- R7-proven register footprint.)
// ---------------------------------------------------------------------------
__global__ __launch_bounds__(256) void k_prep_B(const float* __restrict__ Dre,
                                                const float* __restrict__ Dim,
                                                const float* __restrict__ ker,
                                                u32* __restrict__ yhb) {
    __shared__ float Ds[8][24];
    int t0  = blockIdx.x * 8;
    int tid = threadIdx.x;
    if (tid < 192) {
        int rr = tid / 24, jj = tid - rr * 24;
        Ds[rr][jj] = (jj < 12) ? Dre[(t0 + rr) * 12 + jj] : Dim[(t0 + rr) * 12 + jj - 12];
    }
    __syncthreads();
    for (int rep = 0; rep < 8; rep++) {
        int io = rep * 256 + tid;
        const float4* kp = (const float4*)(ker + io * 12);
        float4 ka = kp[0], kb = kp[1], kc = kp[2];
        float kv[12] = {ka.x, ka.y, ka.z, ka.w, kb.x, kb.y, kb.z, kb.w,
                        kc.x, kc.y, kc.z, kc.w};
#pragma unroll
        for (int rr = 0; rr < 8; rr++) {
            float sr = 0.f, si = 0.f;
#pragma unroll
            for (int j = 0; j < 12; j++) {
                sr += Ds[rr][j]      * kv[j];
                si += Ds[rr][12 + j] * kv[j];
            }
            yhb[(size_t)(t0 + rr) * 2048 + io] = pack2bf(sr, si);
        }
    }
}

// ---------------------------------------------------------------------------
// Fused beta-contraction + bf16 A-fragment pack. Xfb is Hermitian-half:
// rows ma 0..15 stored; ma>=17 read as conj(Xf[32-ma][(32-ng)&31]).
// Grid: (ma 32) x (zig 64) = 2048 blocks; thread = (zil 2, lq 4, ng 32).
// ---------------------------------------------------------------------------
__global__ __launch_bounds__(256) void k_beta_A(const u32* __restrict__ Xfb,
                                                const float* __restrict__ wf,
                                                u16* __restrict__ Ab) {
    int ma  = blockIdx.x >> 6;
    int zig = blockIdx.x & 63;
    int tid = threadIdx.x;
    int ng  = tid & 31;
    int lq  = (tid >> 5) & 3;
    int zil = tid >> 7;
    int zi  = zig * 2 + zil;
    int z = zi >> 5, i = zi & 31;
    int mh = (ma <= 15) ? ma : ma - 32;
    int nh = (ng <= 15) ? ng : ng - 32;
    int am = mh < 0 ? -mh : mh;
    int an = nh < 0 ? -nh : nh;
    int l0 = am > an ? am : an;
    int lb = lq * 4;

    int isconj = (ma > 16);
    int mau = isconj ? (32 - ma) : ma;
    int ngu = isconj ? ((32 - ng) & 31) : ng;
    if (mau > 15) { mau = 0; ngu = 0; }   // ma==16: l0==16, values unused

    int tl[4];
#pragma unroll
    for (int j = 0; j < 4; j++) {
        int l = lb + j;
        tl[j] = LB[l] + (mh + l) * (2 * l + 1) + (nh + l);
    }
    float2 acc[4];
#pragma unroll
    for (int j = 0; j < 4; j++) acc[j] = make_float2(0.f, 0.f);

    const u32* xp = Xfb + (size_t)zi * 32 * 512 + mau * 32 + ngu;
    float sgn = isconj ? -1.f : 1.f;
#pragma unroll 4
    for (int b = 0; b < 32; b++) {
        u32 pv = xp[(size_t)b * 512];
        float vx = __uint_as_float(pv << 16);
        float vy = sgn * __uint_as_float(pv & 0xffff0000u);
        const float* wfb = wf + b * LTOT;
#pragma unroll
        for (int j = 0; j < 4; j++) {
            if (lb + j >= l0) {
                float w = wfb[tl[j]];
                acc[j].x += w * vx;
                acc[j].y += w * vy;
            }
        }
    }
    int s_i  = i >> 4;
    int kl   = 2 * (i & 15);
    int joff = kl & 7;
    int Lhi  = (kl >> 3) << 4;
#pragma unroll
    for (int j = 0; j < 4; j++) {
        int l = lb + j;
        if (l >= l0) {
            int mi = mh + l, ni = nh + l;
            int s   = 2 * ni + s_i;
            int row = 4 * mi + z;
            u32 pack = pack2bf(acc[j].x, acc[j].y);
            size_t off = (size_t)8192 * l * l + (size_t)s * 4096
                       + ((row >> 4) << 9) + ((Lhi + (row & 15)) << 3) + joff;
            *(u32*)(Ab + off) = pack;
        }
    }
}

// ---------------------------------------------------------------------------
// MFMA GEMM. 512 blocks = sum_l 2*(2l+1), big l first: block = (l, n, oh).
// Output transposed: zh_T[zo][t] (float pairs).
// ---------------------------------------------------------------------------
__global__ __launch_bounds__(256) void k_gemm(const u16* __restrict__ Ab,
                                              const u32* __restrict__ yhb,
                                              float* __restrict__ zhT) {
    __shared__ __align__(16) u16 As[4096];
    __shared__ __align__(16) u16 Bs[2048];

    int rem = blockIdx.x, l, nl = 1;
    for (l = 15; l >= 0; l--) {
        nl = 2 * l + 1;
        int c = nl * 2;
        if (rem < c) break;
        rem -= c;
    }
    int n  = rem >> 1;
    int oh = rem & 1;
    int base = LB[l];
    const u16* Ag = Ab + (size_t)8192 * l * l;
    int S = 2 * nl;

    int tid = threadIdx.x, lane = tid & 63, w = tid >> 6;

    int kh = (tid >> 4) & 3;
    int nu = ((tid >> 6) << 4) + (tid & 15);
    int oo = (oh << 5) + (nu >> 1);
    int cc = nu & 1;

    floatx4 acc[2][4];
#pragma unroll
    for (int a = 0; a < 2; a++)
#pragma unroll
        for (int b = 0; b < 4; b++) acc[a][b] = (floatx4)0.f;

    for (int s = 0; s < S; s++) {
        const uint4* ap = (const uint4*)(Ag + (size_t)s * 4096);
        uint4 a0 = ap[tid * 2], a1 = ap[tid * 2 + 1];
        int k = s >> 1, ih = s & 1;
        const u32* yr = yhb + (size_t)(base + k * nl + n) * 2048
                        + (((ih << 4) + (kh << 2)) << 6) + oo;
        u32 b0 = yr[0], b1 = yr[64], b2 = yr[128], b3 = yr[192];
        u32 p0, p1, p2, p3;
        if (cc == 0) {
            p0 = (b0 & 0xffffu) | ((b0 >> 16) << 16 ^ 0x80000000u);
            p1 = (b1 & 0xffffu) | ((b1 >> 16) << 16 ^ 0x80000000u);
            p2 = (b2 & 0xffffu) | ((b2 >> 16) << 16 ^ 0x80000000u);
            p3 = (b3 & 0xffffu) | ((b3 >> 16) << 16 ^ 0x80000000u);
        } else {
            p0 = (b0 >> 16) | (b0 << 16);
            p1 = (b1 >> 16) | (b1 << 16);
            p2 = (b2 >> 16) | (b2 << 16);
            p3 = (b3 >> 16) | (b3 << 16);
        }
        {
            uint4* aq = (uint4*)&As[tid << 4];
            aq[0] = a0; aq[1] = a1;
            *(uint4*)&Bs[tid << 3] = make_uint4(p0, p1, p2, p3);
        }
        __syncthreads();
        short8 af0 = *(const short8*)&As[((w << 1) + 0) * 512 + (lane << 3)];
        short8 af1 = *(const short8*)&As[((w << 1) + 1) * 512 + (lane << 3)];
#pragma unroll
        for (int nt = 0; nt < 4; nt++) {
            short8 bf = *(const short8*)&Bs[nt * 512 + (lane << 3)];
            acc[0][nt] = __builtin_amdgcn_mfma_f32_16x16x32_bf16(af0, bf, acc[0][nt], 0, 0, 0);
            acc[1][nt] = __builtin_amdgcn_mfma_f32_16x16x32_bf16(af1, bf, acc[1][nt], 0, 0, 0);
        }
        __syncthreads();
    }

    int q = lane >> 4, cn = lane & 15;
#pragma unroll
    for (int mt = 0; mt < 2; mt++) {
#pragma unroll
        for (int nt = 0; nt < 4; nt++) {
            int nu2 = (nt << 4) + cn;
            int o2  = (oh << 5) + (nu2 >> 1);
            int c2  = nu2 & 1;
#pragma unroll
            for (int r = 0; r < 4; r++) {
                int R = (w << 5) + (mt << 4) + (q << 2) + r;
                int m = R >> 2, z = R & 3;
                if (m < nl) {
                    int t  = base + m * nl + n;
                    int zo = (z << 6) + o2;
                    zhT[((size_t)zo * LTOT + t) * 2 + c2] = acc[mt][nt][r];
                }
            }
        }
    }
}

// ---------------------------------------------------------------------------
// Inverse, 4 betas per block: shared zv loads across betas (1 zv + 4 w loads
// per 16 FMA), direct pass-2 global write (no LDS staging).
// Grid: 2048 = (zo 256) x (bq 8); 256 threads; LDS ~17 KB.
// ---------------------------------------------------------------------------
__global__ __launch_bounds__(256) void k_inv2(const float2* __restrict__ zhT,
                                              const float* __restrict__ wi,
                                              const float* __restrict__ bias,
                                              float* __restrict__ out) {
    __shared__ float2 Pb[4 * 528];   // plane p at p*528, rows ma 0..15 stride 33
    __shared__ float Wc[32], Ws[32];
    int tid = threadIdx.x;
    int zo = blockIdx.x >> 3;
    int bq = blockIdx.x & 7;
    int b0 = bq * 4;
    if (tid < 32) {
        float sv, cv;
        sincosf(6.28318530717958647692f * (float)tid / 32.0f, &sv, &cv);
        Wc[tid] = cv; Ws[tid] = sv;
    }
    // ---- gather: thread = (ng 32, rq 8); 2 ma-rows; 4 betas share each zv
    {
        int ng = tid & 31, rq = tid >> 5;
        int nh = (ng <= 15) ? ng : ng - 32;
        int an = nh < 0 ? -nh : nh;
        const float2* zr = zhT + (size_t)zo * LTOT;
        const float* w0p = wi + (size_t)b0 * LTOT;
        const float* w1p = w0p + LTOT;
        const float* w2p = w1p + LTOT;
        const float* w3p = w2p + LTOT;
#pragma unroll
        for (int mr = 0; mr < 2; mr++) {
            int ma = rq + 8 * mr;
            int l0 = ma > an ? ma : an;
            float2 a0 = make_float2(0.f, 0.f), a1 = a0, a2 = a0, a3 = a0;
#pragma unroll
            for (int l = 0; l < 16; l++) {
                if (l >= l0) {
                    int t = LB[l] + (ma + l) * (2 * l + 1) + (nh + l);
                    float2 zv = zr[t];
                    float f0 = w0p[t], f1 = w1p[t], f2 = w2p[t], f3 = w3p[t];
                    a0.x += f0 * zv.x; a0.y += f0 * zv.y;
                    a1.x += f1 * zv.x; a1.y += f1 * zv.y;
                    a2.x += f2 * zv.x; a2.y += f2 * zv.y;
                    a3.x += f3 * zv.x; a3.y += f3 * zv.y;
                }
            }
            int po = ma * 33 + ng;
            Pb[po]            = a0;
            Pb[528 + po]      = a1;
            Pb[2 * 528 + po]  = a2;
            Pb[3 * 528 + po]  = a3;
        }
    }
    __syncthreads();
    // ---- pass 1 (ng -> g), radix-2, in-place: 64 rows x 8 thr = 512 tasks
#pragma unroll
    for (int it = 0; it < 2; it++) {
        int task = tid + it * 256;
        int rowid = task >> 3, q = task & 7;
        float2* prow = &Pb[(rowid >> 4) * 528 + (rowid & 15) * 33];
        float2 row[32];
#pragma unroll
        for (int ngi = 0; ngi < 32; ngi++) row[ngi] = prow[ngi];
        float2 outv[4];
#pragma unroll
        for (int kk = 0; kk < 2; kk++) {
            int k = q + kk * 8;
            float2 E = make_float2(0.f, 0.f), O = make_float2(0.f, 0.f);
#pragma unroll
            for (int h = 0; h < 16; h++) {
                int idx = (2 * h * k) & 31;
                float c = Wc[idx], s = Ws[idx];
                float2 e = row[2 * h], o = row[2 * h + 1];
                E.x += e.x * c - e.y * s;  E.y += e.x * s + e.y * c;
                O.x += o.x * c - o.y * s;  O.y += o.x * s + o.y * c;
            }
            float c = Wc[k], s = Ws[k];
            float2 wO = make_float2(O.x * c - O.y * s, O.x * s + O.y * c);
            outv[kk * 2]     = make_float2(E.x + wO.x, E.y + wO.y);
            outv[kk * 2 + 1] = make_float2(E.x - wO.x, E.y - wO.y);
        }
        prow[q]      = outv[0];
        prow[q + 16] = outv[1];
        prow[q + 8]  = outv[2];
        prow[q + 24] = outv[3];
    }
    __syncthreads();
    // ---- pass 2 (ma -> a): direct store with bias (no staging)
    float bv = bias[zo & 63];
#pragma unroll
    for (int it = 0; it < 2; it++) {
        int task = tid + it * 256;
        int p = task >> 7, rr = task & 127;
        int qa = rr >> 5, g = rr & 31;
        float2 col[16];
        const float2* pc = &Pb[p * 528];
#pragma unroll
        for (int ma = 0; ma < 16; ma++) col[ma] = pc[ma * 33 + g];
        float* dst = out + (size_t)zo * 32768 + (size_t)(b0 + p) * 1024;
#pragma unroll
        for (int jj = 0; jj < 4; jj++) {
            int a = qa * 4 + jj;
            float Ea = col[0].x;
            float Oa = 0.f;
#pragma unroll
            for (int j = 1; j < 8; j++) {
                int idx = ((2 * j) * a) & 31;
                Ea += 2.f * (col[2 * j].x * Wc[idx] - col[2 * j].y * Ws[idx]);
            }
#pragma unroll
            for (int j = 0; j < 8; j++) {
                int idx = ((2 * j + 1) * a) & 31;
                Oa += 2.f * (col[2 * j + 1].x * Wc[idx] - col[2 * j + 1].y * Ws[idx]);
            }
            dst[a * 32 + g]        = (Ea + Oa) * (1.f / 1024.f) + bv;
            dst[(a + 16) * 32 + g] = (Ea - Oa) * (1.f / 1024.f) + bv;
        }
    }
}

// ---------------------------------------------------------------------------
extern "C" void kernel_launch(void* const* d_in, const int* in_sizes, int n_in,
                              void* d_out, int out_size, void* d_ws, size_t ws_size,
                              hipStream_t stream) {
    const float* x    = (const float*)d_in[0];
    const float* ker  = (const float*)d_in[1];
    const float* bias = (const float*)d_in[2];
    const float* wf   = (const float*)d_in[3];
    const float* wi   = (const float*)d_in[4];
    const float* Dre  = (const float*)d_in[5];
    const float* Dim  = (const float*)d_in[6];
    float* out = (float*)d_out;

    // layout: yhb 44.7MB | Ab 4.2MB | zh_T 11.2MB; Xfb (8.4MB) aliases zh_T.
    char* ws = (char*)d_ws;
    u32*    yhb = (u32*)ws;
    u16*    Ab  = (u16*)(ws + 44695552);
    float*  zhT = (float*)(ws + 44695552 + 4194304);
    u32*    Xfb = (u32*)zhT;   // disjoint lifetime vs zh_T

    hipLaunchKernelGGL(k_fft_fwd, dim3(4096), dim3(512), 0, stream, x, Xfb);
    hipLaunchKernelGGL(k_prep_B,  dim3(682),  dim3(256), 0, stream, Dre, Dim, ker, yhb);
    hipLaunchKernelGGL(k_beta_A,  dim3(2048), dim3(256), 0, stream, Xfb, wf, Ab);
    hipLaunchKernelGGL(k_gemm,    dim3(512),  dim3(256), 0, stream, Ab, yhb, zhT);
    hipLaunchKernelGGL(k_inv2,    dim3(2048), dim3(256), 0, stream,
                       (const float2*)zhT, wi, bias, out);
}